// Round 6
// baseline (498.985 us; speedup 1.0000x reference)
//
#include <hip/hip_runtime.h>

#define N_NODES 50000
#define N_EDGES 1000000
#define NB      128         // edge chunks
#define CHUNK   7813        // 128*7813 = 1,000,064 >= E
#define NQ      8           // node ranges per chunk (blockIdx.y)
#define QN      6256        // words per range (16B-aligned); 8*6256 = 50048 >= N
#define NBLK2   196         // ceil(50000/256)

// ---- ws layout (bytes) ----
// part[NB][50000] uint (25.6 MB) lives at 0 and is DEAD after k_fill2;
// agg[50000][576] float (115.2 MB) reuses offset 0 after the build.
#define A_PART    0
#define A_AGG     0
#define A_DEGP    115200000  // uint[50000] packed: deg_in<<16 | deg_out
#define A_ROWPTR  115400000  // int[50001]
#define A_BSUM    115600128  // int[196]
#define A_BBASE   115601024  // int[196]
#define A_CSR     115601920  // int2[1e6]: (src, etype)
#define A_HS      123601920  // float[50000*64]
#define A_WALL    136401920  // float[9*64*64]  (ends 136,549,376)

typedef unsigned int uint32;

// K0: Wall[r][i][o] = sum_b comp[r][b]*basis[b][i][o]; Wall[8] = loop_weight
__global__ void k_wall(const float* __restrict__ comp, const float* __restrict__ basis,
                       const float* __restrict__ loopw, float* __restrict__ Wall) {
    int idx = blockIdx.x * 256 + threadIdx.x;
    if (idx >= 9 * 4096) return;
    int r = idx >> 12, io = idx & 4095;
    float acc;
    if (r < 8) {
        acc = 0.f;
        #pragma unroll
        for (int b = 0; b < 30; ++b) acc += comp[r * 30 + b] * basis[b * 4096 + io];
    } else {
        acc = loopw[io];
    }
    Wall[idx] = acc;
}

// K1: per-(chunk, node-range) packed histogram via LDS atomics.
__global__ __launch_bounds__(256) void k_hist2(const int* __restrict__ ei,
                                               uint32* __restrict__ part) {
    __shared__ __align__(16) uint32 h[QN];
    int t = threadIdx.x, b = blockIdx.x, q = blockIdx.y;
    int lo = q * QN;
    int nq = N_NODES - lo; if (nq > QN) nq = QN;
    int4* h4 = (int4*)h;
    for (int i = t; i < QN / 4; i += 256) h4[i] = make_int4(0, 0, 0, 0);
    __syncthreads();
    int e0 = b * CHUNK, e1 = e0 + CHUNK;
    if (e1 > N_EDGES) e1 = N_EDGES;
    for (int e = e0 + t; e < e1; e += 256) {
        int s = ei[e], d = ei[N_EDGES + e];
        unsigned rs = (unsigned)(s - lo), rd = (unsigned)(d - lo);
        if (rs < (unsigned)QN) atomicAdd(&h[rs], 1u);
        if (rd < (unsigned)QN) atomicAdd(&h[rd], 0x10000u);
    }
    __syncthreads();
    int4* d4 = (int4*)(part + b * N_NODES + lo);
    const int4* s4 = (const int4*)h;
    for (int i = t; i < nq / 4; i += 256) d4[i] = s4[i];
}

// K2: degp[v] = sum_b part[b][v]; block sums of deg_in for the scan.
__global__ __launch_bounds__(256) void k_merge(const uint32* __restrict__ part,
                                               uint32* __restrict__ degp,
                                               int* __restrict__ bsum) {
    int t = threadIdx.x, v = blockIdx.x * 256 + t;
    uint32 s = 0;
    if (v < N_NODES) {
        #pragma unroll 8
        for (int b = 0; b < NB; ++b) s += part[b * N_NODES + v];
        degp[v] = s;
    }
    int din = (int)(s >> 16);
    int r = din;
    #pragma unroll
    for (int d = 1; d < 64; d <<= 1) r += __shfl_xor(r, d);
    __shared__ int wsum[4];
    int lane = t & 63, wid = t >> 6;
    if (lane == 0) wsum[wid] = r;
    __syncthreads();
    if (t == 0) bsum[blockIdx.x] = wsum[0] + wsum[1] + wsum[2] + wsum[3];
}

// K3: exclusive scan of 196 block sums (single block).
__global__ void k_scanb(const int* __restrict__ bsum, int* __restrict__ bbase) {
    int t = threadIdx.x;
    int v = (t < NBLK2) ? bsum[t] : 0;
    int lane = t & 63, wid = t >> 6;
    int x = v;
    #pragma unroll
    for (int d = 1; d < 64; d <<= 1) {
        int y = __shfl_up(x, d);
        if (lane >= d) x += y;
    }
    __shared__ int wsum[4];
    if (lane == 63) wsum[wid] = x;
    __syncthreads();
    int base = 0;
    for (int w = 0; w < wid; ++w) base += wsum[w];
    if (t < NBLK2) bbase[t] = base + x - v;
}

// K4: rowptr[v]; convert part[b][v] in-place into fill offsets.
__global__ __launch_bounds__(256) void k_base(uint32* __restrict__ part,
                                              const uint32* __restrict__ degp,
                                              const int* __restrict__ bbase,
                                              int* __restrict__ rowptr) {
    int t = threadIdx.x, v = blockIdx.x * 256 + t;
    int din = (v < N_NODES) ? (int)(degp[v] >> 16) : 0;
    int lane = t & 63, wid = t >> 6;
    int x = din;
    #pragma unroll
    for (int d = 1; d < 64; d <<= 1) {
        int y = __shfl_up(x, d);
        if (lane >= d) x += y;
    }
    __shared__ int wsum[4];
    if (lane == 63) wsum[wid] = x;
    __syncthreads();
    int base = bbase[blockIdx.x];
    for (int w = 0; w < wid; ++w) base += wsum[w];
    int start = base + x - din;
    if (v < N_NODES) {
        rowptr[v] = start;
        if (v == N_NODES - 1) rowptr[N_NODES] = start + din;
        uint32 run = (uint32)start;
        for (int b = 0; b < NB; ++b) {
            uint32 p = part[b * N_NODES + v];
            part[b * N_NODES + v] = run;
            run += (p >> 16);
        }
    }
}

// K5: scatter edges into CSR slots; LDS cursors seeded from fillbase.
__global__ __launch_bounds__(256) void k_fill2(const int* __restrict__ ei,
                                               const int* __restrict__ etype,
                                               const uint32* __restrict__ fillbase,
                                               int2* __restrict__ csr) {
    __shared__ __align__(16) uint32 cur[QN];
    int t = threadIdx.x, b = blockIdx.x, q = blockIdx.y;
    int lo = q * QN;
    int nq = N_NODES - lo; if (nq > QN) nq = QN;
    const int4* s4 = (const int4*)(fillbase + b * N_NODES + lo);
    int4* c4 = (int4*)cur;
    for (int i = t; i < nq / 4; i += 256) c4[i] = s4[i];
    __syncthreads();
    int e0 = b * CHUNK, e1 = e0 + CHUNK;
    if (e1 > N_EDGES) e1 = N_EDGES;
    for (int e = e0 + t; e < e1; e += 256) {
        int d = ei[N_EDGES + e];
        unsigned rd = (unsigned)(d - lo);
        if (rd < (unsigned)QN) {
            int s = ei[e], ty = etype[e];
            uint32 pos = atomicAdd(&cur[rd], 1u);
            csr[pos] = make_int2(s, ty);
        }
    }
}

// K6: bucket gather. agg[v][r*64+f] = sum over in-edges of type r of x[src][f];
// bucket 8 = x[v] (self-loop input).
__global__ __launch_bounds__(256) void k_gather1(const float* __restrict__ x,
                                                 const int2* __restrict__ csr,
                                                 const int* __restrict__ rowptr,
                                                 float* __restrict__ agg) {
    int wid = threadIdx.x >> 6, lane = threadIdx.x & 63;
    int v = blockIdx.x * 4 + wid;
    if (v >= N_NODES) return;
    float a0 = 0.f, a1 = 0.f, a2 = 0.f, a3 = 0.f;
    float a4 = 0.f, a5 = 0.f, a6 = 0.f, a7 = 0.f;
#define ACCUM(VAL, TY) { int sty = __builtin_amdgcn_readfirstlane(TY); \
    switch (sty) { \
        case 0: a0 += (VAL); break; case 1: a1 += (VAL); break; \
        case 2: a2 += (VAL); break; case 3: a3 += (VAL); break; \
        case 4: a4 += (VAL); break; case 5: a5 += (VAL); break; \
        case 6: a6 += (VAL); break; default: a7 += (VAL); break; } }
    int j = rowptr[v], end = rowptr[v + 1];
    for (; j + 4 <= end; j += 4) {
        int2 e0 = csr[j], e1 = csr[j + 1], e2 = csr[j + 2], e3 = csr[j + 3];
        float v0 = x[e0.x * 64 + lane], v1 = x[e1.x * 64 + lane];
        float v2 = x[e2.x * 64 + lane], v3 = x[e3.x * 64 + lane];
        ACCUM(v0, e0.y); ACCUM(v1, e1.y); ACCUM(v2, e2.y); ACCUM(v3, e3.y);
    }
    for (; j < end; ++j) {
        int2 e = csr[j];
        float val = x[e.x * 64 + lane];
        ACCUM(val, e.y);
    }
#undef ACCUM
    float* o = agg + (size_t)v * 576 + lane;
    o[0]   = a0; o[64]  = a1; o[128] = a2; o[192] = a3;
    o[256] = a4; o[320] = a5; o[384] = a6; o[448] = a7;
    o[512] = x[v * 64 + lane];
}

// K7: hs = (agg[N,576] @ Wall[576,64] + bias1) * rsqrt(deg_out).
// 256-thread block = 4 waves, 64 nodes. K split across waves: wave w does
// k-chunks {w, w+4, w+8} of 48 k each, staging each 12 KB B-chunk into a
// private LDS quarter (no cross-wave hazard). Lane tile 8n x 8c. Waves 1-3
// spill partial tiles to LDS (reusing the B region), wave 0 reduces + epilogue.
__global__ __launch_bounds__(256, 3) void k_gemm576(const float* __restrict__ agg,
                                                    const float* __restrict__ Wall,
                                                    const uint32* __restrict__ degp,
                                                    const float* __restrict__ bias1,
                                                    float* __restrict__ hs) {
    __shared__ __align__(16) float SB[12288];   // 48 KB: B-chunks, then partials
    int t = threadIdx.x;
    int wave = t >> 6, lane = t & 63;
    int ng = lane >> 3, cg = lane & 7;
    int nbase = blockIdx.x * 64 + ng * 8;
    int c0 = cg * 8;
    const float* Arow[8];
    #pragma unroll
    for (int i = 0; i < 8; ++i) {
        int n = nbase + i; if (n > N_NODES - 1) n = N_NODES - 1;
        Arow[i] = agg + (size_t)n * 576;
    }
    float acc[8][8];
    #pragma unroll
    for (int i = 0; i < 8; ++i)
        #pragma unroll
        for (int c = 0; c < 8; ++c) acc[i][c] = 0.f;

    float* bw = SB + wave * 3072;              // this wave's B region [48k][64c]
    float4 abuf[8], anext[8];
    {
        int ks0 = wave * 48;
        #pragma unroll
        for (int i = 0; i < 8; ++i) abuf[i] = *(const float4*)(Arow[i] + ks0);
    }

    for (int c = 0; c < 3; ++c) {
        int chunk = 4 * c + wave;
        int ks = chunk * 48;
        const float4* srcb = (const float4*)(Wall + ks * 64);
        float4* dstb = (float4*)bw;
        #pragma unroll
        for (int i = 0; i < 12; ++i) dstb[i * 64 + lane] = srcb[i * 64 + lane];
        __syncthreads();                        // aligned across waves (3 per kernel)
        #pragma unroll 1
        for (int k4 = 0; k4 < 48; k4 += 4) {
            int knext = (k4 < 44) ? (ks + k4 + 4)
                                  : ((c < 2) ? (4 * (c + 1) + wave) * 48 : 0);
            #pragma unroll
            for (int i = 0; i < 8; ++i) anext[i] = *(const float4*)(Arow[i] + knext);
            #pragma unroll
            for (int kk = 0; kk < 4; ++kk) {
                float4 bl = *(const float4*)(bw + (k4 + kk) * 64 + c0);
                float4 bh = *(const float4*)(bw + (k4 + kk) * 64 + c0 + 4);
                #pragma unroll
                for (int i = 0; i < 8; ++i) {
                    float av = ((const float*)&abuf[i])[kk];
                    acc[i][0] += av * bl.x; acc[i][1] += av * bl.y;
                    acc[i][2] += av * bl.z; acc[i][3] += av * bl.w;
                    acc[i][4] += av * bh.x; acc[i][5] += av * bh.y;
                    acc[i][6] += av * bh.z; acc[i][7] += av * bh.w;
                }
            }
            #pragma unroll
            for (int i = 0; i < 8; ++i) abuf[i] = anext[i];
        }
    }

    __syncthreads();                            // all waves done with B regions
    if (wave > 0) {
        float* R = SB + (wave - 1) * 4096;      // [64n][64c] partial tile
        #pragma unroll
        for (int i = 0; i < 8; ++i) {
            int row = ng * 8 + i;
            *(float4*)(R + row * 64 + c0)     = make_float4(acc[i][0], acc[i][1], acc[i][2], acc[i][3]);
            *(float4*)(R + row * 64 + c0 + 4) = make_float4(acc[i][4], acc[i][5], acc[i][6], acc[i][7]);
        }
    }
    __syncthreads();
    if (wave != 0) return;
    #pragma unroll
    for (int ww = 0; ww < 3; ++ww) {
        const float* R = SB + ww * 4096;
        #pragma unroll
        for (int i = 0; i < 8; ++i) {
            int row = ng * 8 + i;
            float4 pl = *(const float4*)(R + row * 64 + c0);
            float4 ph = *(const float4*)(R + row * 64 + c0 + 4);
            acc[i][0] += pl.x; acc[i][1] += pl.y; acc[i][2] += pl.z; acc[i][3] += pl.w;
            acc[i][4] += ph.x; acc[i][5] += ph.y; acc[i][6] += ph.z; acc[i][7] += ph.w;
        }
    }
    float4 b1l = *(const float4*)(bias1 + c0);
    float4 b1h = *(const float4*)(bias1 + c0 + 4);
    #pragma unroll
    for (int i = 0; i < 8; ++i) {
        int n = nbase + i;
        if (n < N_NODES) {
            float dg = (float)(degp[n] & 0xffffu);
            if (dg < 1.f) dg = 1.f;
            float rs = rsqrtf(dg);
            float4 o1, o2;
            o1.x = (acc[i][0] + b1l.x) * rs; o1.y = (acc[i][1] + b1l.y) * rs;
            o1.z = (acc[i][2] + b1l.z) * rs; o1.w = (acc[i][3] + b1l.w) * rs;
            o2.x = (acc[i][4] + b1h.x) * rs; o2.y = (acc[i][5] + b1h.y) * rs;
            o2.z = (acc[i][6] + b1h.z) * rs; o2.w = (acc[i][7] + b1h.w) * rs;
            *(float4*)(hs + (size_t)n * 64 + c0) = o1;
            *(float4*)(hs + (size_t)n * 64 + c0 + 4) = o2;
        }
    }
}

// K8: out[v] = (rsqrt(deg_in[v]) * sum_in hs[src]) @ W2 + bias2
__global__ __launch_bounds__(256) void k_layer2(const float* __restrict__ hs,
                                                const int2* __restrict__ csr,
                                                const int* __restrict__ rowptr,
                                                const uint32* __restrict__ degp,
                                                const float* __restrict__ w2,
                                                const float* __restrict__ bias2,
                                                float* __restrict__ out) {
    __shared__ __align__(16) float W2s[64 * 64];
    __shared__ __align__(16) float ys[4 * 64];
    int t = threadIdx.x;
    #pragma unroll
    for (int j = 0; j < 16; ++j) W2s[t + j * 256] = w2[t + j * 256];
    int wid = t >> 6, lane = t & 63;
    int v = blockIdx.x * 4 + wid;
    float acc = 0.f;
    int j = 0, end = 0;
    if (v < N_NODES) { j = rowptr[v]; end = rowptr[v + 1]; }
    for (; j + 4 <= end; j += 4) {
        int r0 = csr[j].x, r1 = csr[j + 1].x, r2 = csr[j + 2].x, r3 = csr[j + 3].x;
        float a0 = hs[r0 * 64 + lane], a1 = hs[r1 * 64 + lane];
        float a2 = hs[r2 * 64 + lane], a3 = hs[r3 * 64 + lane];
        acc += a0; acc += a1; acc += a2; acc += a3;
    }
    for (; j < end; ++j) acc += hs[csr[j].x * 64 + lane];
    if (v < N_NODES) {
        float dg = (float)(degp[v] >> 16);
        if (dg < 1.f) dg = 1.f;
        ys[wid * 64 + lane] = acc * rsqrtf(dg);
    }
    __syncthreads();
    if (v >= N_NODES) return;
    float o = bias2[lane];
    const float* yrow = &ys[wid * 64];
    #pragma unroll 4
    for (int k = 0; k < 64; ++k) o += yrow[k] * W2s[k * 64 + lane];
    out[v * 64 + lane] = o;
}

extern "C" void kernel_launch(void* const* d_in, const int* in_sizes, int n_in,
                              void* d_out, int out_size, void* d_ws, size_t ws_size,
                              hipStream_t stream) {
    const float* x      = (const float*)d_in[0];
    const int*   ei     = (const int*)d_in[1];   // [2E]: src then dst
    const int*   etype  = (const int*)d_in[3];
    const float* basis  = (const float*)d_in[4];
    const float* comp   = (const float*)d_in[5];
    const float* loopw  = (const float*)d_in[6];
    const float* bias1  = (const float*)d_in[7];
    const float* w2     = (const float*)d_in[8];
    const float* bias2  = (const float*)d_in[9];
    float* out = (float*)d_out;

    char* ws = (char*)d_ws;
    uint32* part   = (uint32*)(ws + A_PART);
    float*  agg    = (float*)(ws + A_AGG);     // aliases part; written after fill
    uint32* degp   = (uint32*)(ws + A_DEGP);
    int*    rowptr = (int*)(ws + A_ROWPTR);
    int*    bsum   = (int*)(ws + A_BSUM);
    int*    bbase  = (int*)(ws + A_BBASE);
    int2*   csr    = (int2*)(ws + A_CSR);
    float*  hs     = (float*)(ws + A_HS);
    float*  Wall   = (float*)(ws + A_WALL);

    k_wall<<<144, 256, 0, stream>>>(comp, basis, loopw, Wall);
    k_hist2<<<dim3(NB, NQ), 256, 0, stream>>>(ei, part);
    k_merge<<<NBLK2, 256, 0, stream>>>(part, degp, bsum);
    k_scanb<<<1, 256, 0, stream>>>(bsum, bbase);
    k_base<<<NBLK2, 256, 0, stream>>>(part, degp, bbase, rowptr);
    k_fill2<<<dim3(NB, NQ), 256, 0, stream>>>(ei, etype, part, csr);
    k_gather1<<<N_NODES / 4, 256, 0, stream>>>(x, csr, rowptr, agg);
    k_gemm576<<<(N_NODES + 63) / 64, 256, 0, stream>>>(agg, Wall, degp, bias1, hs);
    k_layer2<<<N_NODES / 4, 256, 0, stream>>>(hs, csr, rowptr, degp, w2, bias2, out);
}

// Round 8
// 353.300 us; speedup vs baseline: 1.4124x; 1.4124x over previous
//
#include <hip/hip_runtime.h>

#define N_NODES 50000
#define N_EDGES 1000000
#define NB      128         // edge chunks
#define CHUNK   7813        // 128*7813 = 1,000,064 >= E
#define NQ      8           // node ranges per chunk (blockIdx.y)
#define QN      6256        // words per range (16B-aligned); 8*6256 = 50048 >= N
#define NBLK2   196         // ceil(50000/256)

// ---- ws layout (bytes) ----
// part[NB][50000] uint (25.6 MB) lives at 0 and is DEAD after k_fill2;
// agg[50000][576] float (115.2 MB) reuses offset 0 after the build.
#define A_PART    0
#define A_AGG     0
#define A_DEGP    115200000  // uint[50000] packed: deg_in<<16 | deg_out
#define A_ROWPTR  115400000  // int[50001]
#define A_BSUM    115600128  // int[196]
#define A_BBASE   115601024  // int[196]
#define A_CSR     115601920  // int2[1e6]: (src, etype)
#define A_HS      123601920  // float[50000*64]
#define A_WALL    136401920  // float[9*64*64]  (ends 136,549,376)

typedef unsigned int uint32;

// K0: Wall[r][i][o] = sum_b comp[r][b]*basis[b][i][o]; Wall[8] = loop_weight
__global__ void k_wall(const float* __restrict__ comp, const float* __restrict__ basis,
                       const float* __restrict__ loopw, float* __restrict__ Wall) {
    int idx = blockIdx.x * 256 + threadIdx.x;
    if (idx >= 9 * 4096) return;
    int r = idx >> 12, io = idx & 4095;
    float acc;
    if (r < 8) {
        acc = 0.f;
        #pragma unroll
        for (int b = 0; b < 30; ++b) acc += comp[r * 30 + b] * basis[b * 4096 + io];
    } else {
        acc = loopw[io];
    }
    Wall[idx] = acc;
}

// K1: per-(chunk, node-range) packed histogram via LDS atomics.
__global__ __launch_bounds__(256) void k_hist2(const int* __restrict__ ei,
                                               uint32* __restrict__ part) {
    __shared__ __align__(16) uint32 h[QN];
    int t = threadIdx.x, b = blockIdx.x, q = blockIdx.y;
    int lo = q * QN;
    int nq = N_NODES - lo; if (nq > QN) nq = QN;
    int4* h4 = (int4*)h;
    for (int i = t; i < QN / 4; i += 256) h4[i] = make_int4(0, 0, 0, 0);
    __syncthreads();
    int e0 = b * CHUNK, e1 = e0 + CHUNK;
    if (e1 > N_EDGES) e1 = N_EDGES;
    for (int e = e0 + t; e < e1; e += 256) {
        int s = ei[e], d = ei[N_EDGES + e];
        unsigned rs = (unsigned)(s - lo), rd = (unsigned)(d - lo);
        if (rs < (unsigned)QN) atomicAdd(&h[rs], 1u);
        if (rd < (unsigned)QN) atomicAdd(&h[rd], 0x10000u);
    }
    __syncthreads();
    int4* d4 = (int4*)(part + b * N_NODES + lo);
    const int4* s4 = (const int4*)h;
    for (int i = t; i < nq / 4; i += 256) d4[i] = s4[i];
}

// K2: degp[v] = sum_b part[b][v]; block sums of deg_in for the scan.
__global__ __launch_bounds__(256) void k_merge(const uint32* __restrict__ part,
                                               uint32* __restrict__ degp,
                                               int* __restrict__ bsum) {
    int t = threadIdx.x, v = blockIdx.x * 256 + t;
    uint32 s = 0;
    if (v < N_NODES) {
        #pragma unroll 8
        for (int b = 0; b < NB; ++b) s += part[b * N_NODES + v];
        degp[v] = s;
    }
    int din = (int)(s >> 16);
    int r = din;
    #pragma unroll
    for (int d = 1; d < 64; d <<= 1) r += __shfl_xor(r, d);
    __shared__ int wsum[4];
    int lane = t & 63, wid = t >> 6;
    if (lane == 0) wsum[wid] = r;
    __syncthreads();
    if (t == 0) bsum[blockIdx.x] = wsum[0] + wsum[1] + wsum[2] + wsum[3];
}

// K3: exclusive scan of 196 block sums (single block).
__global__ void k_scanb(const int* __restrict__ bsum, int* __restrict__ bbase) {
    int t = threadIdx.x;
    int v = (t < NBLK2) ? bsum[t] : 0;
    int lane = t & 63, wid = t >> 6;
    int x = v;
    #pragma unroll
    for (int d = 1; d < 64; d <<= 1) {
        int y = __shfl_up(x, d);
        if (lane >= d) x += y;
    }
    __shared__ int wsum[4];
    if (lane == 63) wsum[wid] = x;
    __syncthreads();
    int base = 0;
    for (int w = 0; w < wid; ++w) base += wsum[w];
    if (t < NBLK2) bbase[t] = base + x - v;
}

// K4: rowptr[v]; convert part[b][v] in-place into fill offsets.
__global__ __launch_bounds__(256) void k_base(uint32* __restrict__ part,
                                              const uint32* __restrict__ degp,
                                              const int* __restrict__ bbase,
                                              int* __restrict__ rowptr) {
    int t = threadIdx.x, v = blockIdx.x * 256 + t;
    int din = (v < N_NODES) ? (int)(degp[v] >> 16) : 0;
    int lane = t & 63, wid = t >> 6;
    int x = din;
    #pragma unroll
    for (int d = 1; d < 64; d <<= 1) {
        int y = __shfl_up(x, d);
        if (lane >= d) x += y;
    }
    __shared__ int wsum[4];
    if (lane == 63) wsum[wid] = x;
    __syncthreads();
    int base = bbase[blockIdx.x];
    for (int w = 0; w < wid; ++w) base += wsum[w];
    int start = base + x - din;
    if (v < N_NODES) {
        rowptr[v] = start;
        if (v == N_NODES - 1) rowptr[N_NODES] = start + din;
        uint32 run = (uint32)start;
        for (int b = 0; b < NB; ++b) {
            uint32 p = part[b * N_NODES + v];
            part[b * N_NODES + v] = run;
            run += (p >> 16);
        }
    }
}

// K5: scatter edges into CSR slots; LDS cursors seeded from fillbase.
__global__ __launch_bounds__(256) void k_fill2(const int* __restrict__ ei,
                                               const int* __restrict__ etype,
                                               const uint32* __restrict__ fillbase,
                                               int2* __restrict__ csr) {
    __shared__ __align__(16) uint32 cur[QN];
    int t = threadIdx.x, b = blockIdx.x, q = blockIdx.y;
    int lo = q * QN;
    int nq = N_NODES - lo; if (nq > QN) nq = QN;
    const int4* s4 = (const int4*)(fillbase + b * N_NODES + lo);
    int4* c4 = (int4*)cur;
    for (int i = t; i < nq / 4; i += 256) c4[i] = s4[i];
    __syncthreads();
    int e0 = b * CHUNK, e1 = e0 + CHUNK;
    if (e1 > N_EDGES) e1 = N_EDGES;
    for (int e = e0 + t; e < e1; e += 256) {
        int d = ei[N_EDGES + e];
        unsigned rd = (unsigned)(d - lo);
        if (rd < (unsigned)QN) {
            int s = ei[e], ty = etype[e];
            uint32 pos = atomicAdd(&cur[rd], 1u);
            csr[pos] = make_int2(s, ty);
        }
    }
}

// K6: bucket gather. agg[v][r*64+f] = sum over in-edges of type r of x[src][f];
// bucket 8 = x[v] (self-loop input).
__global__ __launch_bounds__(256) void k_gather1(const float* __restrict__ x,
                                                 const int2* __restrict__ csr,
                                                 const int* __restrict__ rowptr,
                                                 float* __restrict__ agg) {
    int wid = threadIdx.x >> 6, lane = threadIdx.x & 63;
    int v = blockIdx.x * 4 + wid;
    if (v >= N_NODES) return;
    float a0 = 0.f, a1 = 0.f, a2 = 0.f, a3 = 0.f;
    float a4 = 0.f, a5 = 0.f, a6 = 0.f, a7 = 0.f;
#define ACCUM(VAL, TY) { int sty = __builtin_amdgcn_readfirstlane(TY); \
    switch (sty) { \
        case 0: a0 += (VAL); break; case 1: a1 += (VAL); break; \
        case 2: a2 += (VAL); break; case 3: a3 += (VAL); break; \
        case 4: a4 += (VAL); break; case 5: a5 += (VAL); break; \
        case 6: a6 += (VAL); break; default: a7 += (VAL); break; } }
    int j = rowptr[v], end = rowptr[v + 1];
    for (; j + 4 <= end; j += 4) {
        int2 e0 = csr[j], e1 = csr[j + 1], e2 = csr[j + 2], e3 = csr[j + 3];
        float v0 = x[e0.x * 64 + lane], v1 = x[e1.x * 64 + lane];
        float v2 = x[e2.x * 64 + lane], v3 = x[e3.x * 64 + lane];
        ACCUM(v0, e0.y); ACCUM(v1, e1.y); ACCUM(v2, e2.y); ACCUM(v3, e3.y);
    }
    for (; j < end; ++j) {
        int2 e = csr[j];
        float val = x[e.x * 64 + lane];
        ACCUM(val, e.y);
    }
#undef ACCUM
    float* o = agg + (size_t)v * 576 + lane;
    o[0]   = a0; o[64]  = a1; o[128] = a2; o[192] = a3;
    o[256] = a4; o[320] = a5; o[384] = a6; o[448] = a7;
    o[512] = x[v * 64 + lane];
}

// K7: hs = (agg[N,576] @ Wall[576,64] + bias1) * rsqrt(deg_out).
// R5-proven structure, doubled TLP: 128-thread block = 2 independent waves;
// wave w owns 32 nodes (lane tile 4n x 8c, acc=32 regs); both waves share the
// 16 KB B-chunk stage in LDS. A streamed from global, depth-1 double buffer
// (abuf/anext), exactly the R5 inner-loop pattern. No launch-bounds occupancy
// cap (R6 spill lesson), no rotating prefetch slots (R7 lesson).
__global__ __launch_bounds__(128) void k_gemm576(const float* __restrict__ agg,
                                                 const float* __restrict__ Wall,
                                                 const uint32* __restrict__ degp,
                                                 const float* __restrict__ bias1,
                                                 float* __restrict__ hs) {
    __shared__ __align__(16) float Bs[64 * 64];
    int t = threadIdx.x;
    int wave = t >> 6, lane = t & 63;
    int ng = lane >> 3, cg = lane & 7;   // node-quad group, col-octet
    int nbase = blockIdx.x * 64 + wave * 32 + ng * 4;
    int c0 = cg * 8;
    const float* Arow[4];
    #pragma unroll
    for (int i = 0; i < 4; ++i) {
        int n = nbase + i; if (n > N_NODES - 1) n = N_NODES - 1;
        Arow[i] = agg + (size_t)n * 576;
    }
    float acc[4][8];
    #pragma unroll
    for (int i = 0; i < 4; ++i)
        #pragma unroll
        for (int c = 0; c < 8; ++c) acc[i][c] = 0.f;

    float4 abuf[4], anext[4];
    #pragma unroll
    for (int i = 0; i < 4; ++i) abuf[i] = *(const float4*)(Arow[i]);  // k=0..3

    for (int kc = 0; kc < 9; ++kc) {
        // stage B chunk [64k][64c] = 16 KB, cooperatively across 128 threads
        const float4* srcb = (const float4*)(Wall + kc * 4096);
        float4* dstb = (float4*)Bs;
        #pragma unroll
        for (int i = 0; i < 8; ++i) dstb[i * 128 + t] = srcb[i * 128 + t];
        __syncthreads();
        #pragma unroll 1
        for (int k4 = 0; k4 < 64; k4 += 4) {
            int knext = kc * 64 + k4 + 4;
            if (knext >= 576) knext = 0;           // harmless wrap prefetch
            #pragma unroll
            for (int i = 0; i < 4; ++i) anext[i] = *(const float4*)(Arow[i] + knext);
            #pragma unroll
            for (int kk = 0; kk < 4; ++kk) {
                float4 bl = *(const float4*)(Bs + (k4 + kk) * 64 + c0);
                float4 bh = *(const float4*)(Bs + (k4 + kk) * 64 + c0 + 4);
                #pragma unroll
                for (int i = 0; i < 4; ++i) {
                    float av = ((const float*)&abuf[i])[kk];
                    acc[i][0] += av * bl.x; acc[i][1] += av * bl.y;
                    acc[i][2] += av * bl.z; acc[i][3] += av * bl.w;
                    acc[i][4] += av * bh.x; acc[i][5] += av * bh.y;
                    acc[i][6] += av * bh.z; acc[i][7] += av * bh.w;
                }
            }
            #pragma unroll
            for (int i = 0; i < 4; ++i) abuf[i] = anext[i];
        }
        __syncthreads();
    }

    float4 b1l = *(const float4*)(bias1 + c0);
    float4 b1h = *(const float4*)(bias1 + c0 + 4);
    #pragma unroll
    for (int i = 0; i < 4; ++i) {
        int n = nbase + i;
        if (n < N_NODES) {
            float dg = (float)(degp[n] & 0xffffu);
            if (dg < 1.f) dg = 1.f;
            float rs = rsqrtf(dg);
            float4 o1, o2;
            o1.x = (acc[i][0] + b1l.x) * rs; o1.y = (acc[i][1] + b1l.y) * rs;
            o1.z = (acc[i][2] + b1l.z) * rs; o1.w = (acc[i][3] + b1l.w) * rs;
            o2.x = (acc[i][4] + b1h.x) * rs; o2.y = (acc[i][5] + b1h.y) * rs;
            o2.z = (acc[i][6] + b1h.z) * rs; o2.w = (acc[i][7] + b1h.w) * rs;
            *(float4*)(hs + (size_t)n * 64 + c0) = o1;
            *(float4*)(hs + (size_t)n * 64 + c0 + 4) = o2;
        }
    }
}

// K8: out[v] = (rsqrt(deg_in[v]) * sum_in hs[src]) @ W2 + bias2
__global__ __launch_bounds__(256) void k_layer2(const float* __restrict__ hs,
                                                const int2* __restrict__ csr,
                                                const int* __restrict__ rowptr,
                                                const uint32* __restrict__ degp,
                                                const float* __restrict__ w2,
                                                const float* __restrict__ bias2,
                                                float* __restrict__ out) {
    __shared__ __align__(16) float W2s[64 * 64];
    __shared__ __align__(16) float ys[4 * 64];
    int t = threadIdx.x;
    #pragma unroll
    for (int j = 0; j < 16; ++j) W2s[t + j * 256] = w2[t + j * 256];
    int wid = t >> 6, lane = t & 63;
    int v = blockIdx.x * 4 + wid;
    float acc = 0.f;
    int j = 0, end = 0;
    if (v < N_NODES) { j = rowptr[v]; end = rowptr[v + 1]; }
    for (; j + 4 <= end; j += 4) {
        int r0 = csr[j].x, r1 = csr[j + 1].x, r2 = csr[j + 2].x, r3 = csr[j + 3].x;
        float a0 = hs[r0 * 64 + lane], a1 = hs[r1 * 64 + lane];
        float a2 = hs[r2 * 64 + lane], a3 = hs[r3 * 64 + lane];
        acc += a0; acc += a1; acc += a2; acc += a3;
    }
    for (; j < end; ++j) acc += hs[csr[j].x * 64 + lane];
    if (v < N_NODES) {
        float dg = (float)(degp[v] >> 16);
        if (dg < 1.f) dg = 1.f;
        ys[wid * 64 + lane] = acc * rsqrtf(dg);
    }
    __syncthreads();
    if (v >= N_NODES) return;
    float o = bias2[lane];
    const float* yrow = &ys[wid * 64];
    #pragma unroll 4
    for (int k = 0; k < 64; ++k) o += yrow[k] * W2s[k * 64 + lane];
    out[v * 64 + lane] = o;
}

extern "C" void kernel_launch(void* const* d_in, const int* in_sizes, int n_in,
                              void* d_out, int out_size, void* d_ws, size_t ws_size,
                              hipStream_t stream) {
    const float* x      = (const float*)d_in[0];
    const int*   ei     = (const int*)d_in[1];   // [2E]: src then dst
    const int*   etype  = (const int*)d_in[3];
    const float* basis  = (const float*)d_in[4];
    const float* comp   = (const float*)d_in[5];
    const float* loopw  = (const float*)d_in[6];
    const float* bias1  = (const float*)d_in[7];
    const float* w2     = (const float*)d_in[8];
    const float* bias2  = (const float*)d_in[9];
    float* out = (float*)d_out;

    char* ws = (char*)d_ws;
    uint32* part   = (uint32*)(ws + A_PART);
    float*  agg    = (float*)(ws + A_AGG);     // aliases part; written after fill
    uint32* degp   = (uint32*)(ws + A_DEGP);
    int*    rowptr = (int*)(ws + A_ROWPTR);
    int*    bsum   = (int*)(ws + A_BSUM);
    int*    bbase  = (int*)(ws + A_BBASE);
    int2*   csr    = (int2*)(ws + A_CSR);
    float*  hs     = (float*)(ws + A_HS);
    float*  Wall   = (float*)(ws + A_WALL);

    k_wall<<<144, 256, 0, stream>>>(comp, basis, loopw, Wall);
    k_hist2<<<dim3(NB, NQ), 256, 0, stream>>>(ei, part);
    k_merge<<<NBLK2, 256, 0, stream>>>(part, degp, bsum);
    k_scanb<<<1, 256, 0, stream>>>(bsum, bbase);
    k_base<<<NBLK2, 256, 0, stream>>>(part, degp, bbase, rowptr);
    k_fill2<<<dim3(NB, NQ), 256, 0, stream>>>(ei, etype, part, csr);
    k_gather1<<<N_NODES / 4, 256, 0, stream>>>(x, csr, rowptr, agg);
    k_gemm576<<<(N_NODES + 63) / 64, 128, 0, stream>>>(agg, Wall, degp, bias1, hs);
    k_layer2<<<N_NODES / 4, 256, 0, stream>>>(hs, csr, rowptr, degp, w2, bias2, out);
}